// Round 5
// baseline (583.054 us; speedup 1.0000x reference)
//
#include <hip/hip_runtime.h>
#include <hip/hip_bf16.h>

// GCN: 2x GCNConv(+self-loops, sym-norm) + ReLU, then Linear(64->1).
// N=100000 nodes, E=1600000 edges, IN=128, HID=64, OUT=1.
//
//  - R4 fix: random 4B scatter/atomics (count_deg + scatter_edges) caused
//    ~64B/edge HBM writeback (106-155MB for ~13MB logical) from cross-XCD
//    L2 line bouncing. Replaced by XCD-partitioned bucketed counting sort:
//    bin_edges (bucket = dst>>6, partition by bucket&7 == blockIdx&7) ->
//    scan_buckets -> build_csr (per-bucket LDS histogram/scan/scatter).
//    deg/disqrt fall out of the bucket histogram (count_deg eliminated).
//  - norm factored into GEMM epilogue: out[d]=dq_d*(Ts[d]+sum Ts[s]).
//  - 64x64 tiled GEMM, 4x4 register blocking, LDS-staged transposed X.
//  - agg: one wave per node, edge loop unrolled x8, scalar gather base.

#define IN_DIM 128
#define HID 64
#define CAP 1536   // bucket capacity: mean 1024, sigma 32 -> +16 sigma

// ---------------- bin edges into 64-node buckets (XCD-partitioned) ----------------
__global__ __launch_bounds__(256) void bin_edges(const int* __restrict__ src,
                                                 const int* __restrict__ dst,
                                                 int* __restrict__ bcnt,
                                                 int2* __restrict__ pairs, int E) {
    const int part = blockIdx.x & 7;        // assumed XCD (round-robin); perf-only
    const int pb   = blockIdx.x >> 3;       // block index within partition
    const int npb  = gridDim.x >> 3;        // blocks per partition
    for (int i = pb * 256 + (int)threadIdx.x; i < E; i += npb * 256) {
        int d = dst[i];
        int b = d >> 6;
        if ((b & 7) == part) {
            int p = atomicAdd(&bcnt[b], 1);
            if (p < CAP) pairs[(size_t)b * CAP + p] = make_int2(src[i], d & 63);
        }
    }
}

// ---------------- exclusive scan over bucket counts (nbk <= 2048) ----------------
__global__ __launch_bounds__(1024) void scan_buckets(const int* __restrict__ bcnt,
                                                     int* __restrict__ bbase,
                                                     int* __restrict__ row_off,
                                                     int nbk, int N) {
    __shared__ int s[1024];
    int t = threadIdx.x;
    int i0 = 2 * t, i1 = 2 * t + 1;
    int v0 = (i0 < nbk) ? min(bcnt[i0], CAP) : 0;
    int v1 = (i1 < nbk) ? min(bcnt[i1], CAP) : 0;
    int sum = v0 + v1;
    s[t] = sum;
    __syncthreads();
#pragma unroll
    for (int o = 1; o < 1024; o <<= 1) {
        int add = (t >= o) ? s[t - o] : 0;
        __syncthreads();
        s[t] += add;
        __syncthreads();
    }
    int excl = s[t] - sum;
    if (i0 < nbk) bbase[i0] = excl;
    if (i1 < nbk) bbase[i1] = excl + v0;
    if (t == 1023) row_off[N] = s[t];  // total edges
}

// ---------------- per-bucket CSR build: histogram, scan, scatter ----------------
__global__ __launch_bounds__(256) void build_csr(const int2* __restrict__ pairs,
                                                 const int* __restrict__ bcnt,
                                                 const int* __restrict__ bbase,
                                                 int* __restrict__ row_off,
                                                 float* __restrict__ disqrt,
                                                 int* __restrict__ col, int N) {
    __shared__ int s_src[CAP];
    __shared__ unsigned char s_loc[CAP];
    __shared__ int s_cnt[64], s_cur[64];
    int b = blockIdx.x;
    int t = threadIdx.x;
    int cnt = min(bcnt[b], CAP);
    int base = bbase[b];
    int node0 = b << 6;
    if (t < 64) s_cnt[t] = 0;
    __syncthreads();
    for (int i = t; i < cnt; i += 256) {
        int2 p = pairs[(size_t)b * CAP + i];
        s_src[i] = p.x;
        s_loc[i] = (unsigned char)p.y;
        atomicAdd(&s_cnt[p.y], 1);
    }
    __syncthreads();
    if (t < 64) {
        int v = s_cnt[t];
        int incl = v;
#pragma unroll
        for (int o = 1; o < 64; o <<= 1) {
            int u = __shfl_up(incl, o, 64);
            if (t >= o) incl += u;
        }
        s_cur[t] = incl - v;  // exclusive offset within bucket
        int node = node0 + t;
        if (node < N) {
            row_off[node] = base + incl - v;
            disqrt[node]  = rsqrtf((float)(v + 1));  // +1 self-loop
        }
    }
    __syncthreads();
    for (int i = t; i < cnt; i += 256) {
        int loc = s_loc[i];
        int pos = atomicAdd(&s_cur[loc], 1);   // LDS atomic
        col[base + pos] = s_src[i];            // within bucket's 6KB window
    }
}

// ---------------- tiled GEMM: Ts[n,64] = (X[n,K] @ W[K,64]) * disqrt[n] ----------------
template <int K>
__global__ __launch_bounds__(256) void gemm_tile(const float* __restrict__ X,
                                                 const float* __restrict__ W,
                                                 const float* __restrict__ disqrt,
                                                 float* __restrict__ Ts, int n) {
    __shared__ float xs[32][68];   // [k][m]; stride 68 floats keeps rows 16B-aligned
    __shared__ float ws[32][64];   // [k][c]
    const int tid  = threadIdx.x;
    const int nIdx = tid & 15;     // cols 4*nIdx..+3
    const int mIdx = tid >> 4;     // nodes 4*mIdx..+3
    const int m0   = blockIdx.x * 64;
    float acc[4][4] = {};
    for (int kc = 0; kc < K; kc += 32) {
        int f = tid;
#pragma unroll
        for (int i = 0; i < 2; ++i, f += 256) {
            int r  = f >> 3;           // 0..63
            int kq = f & 7;            // float4 within chunk
            int row = m0 + r;
            float4 g = make_float4(0.f, 0.f, 0.f, 0.f);
            if (row < n) g = *(const float4*)(X + (size_t)row * K + kc + 4 * kq);
            xs[4 * kq + 0][r] = g.x;
            xs[4 * kq + 1][r] = g.y;
            xs[4 * kq + 2][r] = g.z;
            xs[4 * kq + 3][r] = g.w;
        }
        f = tid;
#pragma unroll
        for (int i = 0; i < 2; ++i, f += 256) {
            int kk = f >> 4;           // 0..31
            int cq = f & 15;           // 0..15
            *(float4*)&ws[kk][4 * cq] =
                *(const float4*)(W + (size_t)(kc + kk) * 64 + 4 * cq);
        }
        __syncthreads();
#pragma unroll 4
        for (int k = 0; k < 32; ++k) {
            float4 a = *(const float4*)&xs[k][4 * mIdx];
            float4 b = *(const float4*)&ws[k][4 * nIdx];
            const float* ap = (const float*)&a;
            const float* bp = (const float*)&b;
#pragma unroll
            for (int mi = 0; mi < 4; ++mi)
#pragma unroll
                for (int ni = 0; ni < 4; ++ni)
                    acc[mi][ni] += ap[mi] * bp[ni];
        }
        __syncthreads();
    }
#pragma unroll
    for (int mi = 0; mi < 4; ++mi) {
        int row = m0 + 4 * mIdx + mi;
        if (row < n) {
            float s = disqrt[row];
            *(float4*)(Ts + (size_t)row * 64 + 4 * nIdx) =
                make_float4(acc[mi][0] * s, acc[mi][1] * s,
                            acc[mi][2] * s, acc[mi][3] * s);
        }
    }
}

// ---------------- aggregation: one wave per node, 8 gathers in flight ----------------
// out[d] = relu(disqrt[d] * (Ts[d] + sum_e Ts[col[e]]) + bias)
template <bool FUSE_FC>
__global__ __launch_bounds__(256) void agg_kernel(const float* __restrict__ Ts,
                                                  const int* __restrict__ row_off,
                                                  const int* __restrict__ col,
                                                  const float* __restrict__ disqrt,
                                                  const float* __restrict__ bias,
                                                  const float* __restrict__ wfc,
                                                  const float* __restrict__ bfc,
                                                  float* __restrict__ out, int n) {
    int node = blockIdx.x * 4 + (threadIdx.x >> 6);
    if (node >= n) return;
    int lane = threadIdx.x & 63;
    float acc = Ts[(size_t)node * HID + lane];  // self-loop (pre-scaled)
    int beg = __builtin_amdgcn_readfirstlane(row_off[node]);
    int end = __builtin_amdgcn_readfirstlane(row_off[node + 1]);
    int i = beg;
    for (; i + 8 <= end; i += 8) {
        int s0 = __builtin_amdgcn_readfirstlane(col[i + 0]);
        int s1 = __builtin_amdgcn_readfirstlane(col[i + 1]);
        int s2 = __builtin_amdgcn_readfirstlane(col[i + 2]);
        int s3 = __builtin_amdgcn_readfirstlane(col[i + 3]);
        int s4 = __builtin_amdgcn_readfirstlane(col[i + 4]);
        int s5 = __builtin_amdgcn_readfirstlane(col[i + 5]);
        int s6 = __builtin_amdgcn_readfirstlane(col[i + 6]);
        int s7 = __builtin_amdgcn_readfirstlane(col[i + 7]);
        float g0 = Ts[(size_t)s0 * HID + lane];
        float g1 = Ts[(size_t)s1 * HID + lane];
        float g2 = Ts[(size_t)s2 * HID + lane];
        float g3 = Ts[(size_t)s3 * HID + lane];
        float g4 = Ts[(size_t)s4 * HID + lane];
        float g5 = Ts[(size_t)s5 * HID + lane];
        float g6 = Ts[(size_t)s6 * HID + lane];
        float g7 = Ts[(size_t)s7 * HID + lane];
        acc += g0; acc += g1; acc += g2; acc += g3;
        acc += g4; acc += g5; acc += g6; acc += g7;
    }
    for (; i < end; ++i) {
        int s = __builtin_amdgcn_readfirstlane(col[i]);
        acc += Ts[(size_t)s * HID + lane];
    }
    float r = fmaxf(acc * disqrt[node] + bias[lane], 0.f);
    if (!FUSE_FC) {
        out[(size_t)node * HID + lane] = r;
    } else {
        float v = r * wfc[lane];
        v += __shfl_down(v, 32, 64);
        v += __shfl_down(v, 16, 64);
        v += __shfl_down(v, 8, 64);
        v += __shfl_down(v, 4, 64);
        v += __shfl_down(v, 2, 64);
        v += __shfl_down(v, 1, 64);
        if (lane == 0) out[node] = v + bfc[0];
    }
}

extern "C" void kernel_launch(void* const* d_in, const int* in_sizes, int n_in,
                              void* d_out, int out_size, void* d_ws, size_t ws_size,
                              hipStream_t stream) {
    const float* x   = (const float*)d_in[0];
    const int*   ei  = (const int*)d_in[1];
    const float* W1  = (const float*)d_in[2];
    const float* b1  = (const float*)d_in[3];
    const float* W2  = (const float*)d_in[4];
    const float* b2  = (const float*)d_in[5];
    const float* Wfc = (const float*)d_in[6];
    const float* bfc = (const float*)d_in[7];
    float* out = (float*)d_out;

    const int N = in_sizes[0] / IN_DIM;
    const int E = in_sizes[1] / 2;
    const int* src = ei;
    const int* dst = ei + E;
    const int NBK = (N + 63) >> 6;   // 64-node buckets (<= 2048)

    // ---- workspace carve-up (256B aligned) ----
    char* w = (char*)d_ws;
    auto alloc = [&](size_t bytes) {
        void* p = (void*)w;
        w += (bytes + 255) & ~(size_t)255;
        return p;
    };
    int*   row_off = (int*)alloc((size_t)(N + 1) * 4);
    float* disqrt  = (float*)alloc((size_t)N * 4);
    int*   bcnt    = (int*)alloc((size_t)NBK * 4);
    int*   bbase   = (int*)alloc((size_t)NBK * 4);
    int*   col     = (int*)alloc((size_t)E * 4);
    float* t1      = (float*)alloc((size_t)N * HID * 4);  // reused: pairs, then Ts
    float* h1      = (float*)alloc((size_t)N * HID * 4);
    int2*  pairs   = (int2*)t1;  // NBK*CAP*8 = 19.2MB <= N*HID*4 = 25.6MB

    // ---- build CSR (bucketed counting sort) ----
    hipMemsetAsync(bcnt, 0, (size_t)NBK * 4, stream);
    bin_edges<<<1024, 256, 0, stream>>>(src, dst, bcnt, pairs, E);
    scan_buckets<<<1, 1024, 0, stream>>>(bcnt, bbase, row_off, NBK, N);
    build_csr<<<NBK, 256, 0, stream>>>(pairs, bcnt, bbase, row_off, disqrt, col, N);

    // ---- layer 1 ----
    gemm_tile<IN_DIM><<<(N + 63) / 64, 256, 0, stream>>>(x, W1, disqrt, t1, N);
    agg_kernel<false><<<(N + 3) / 4, 256, 0, stream>>>(t1, row_off, col, disqrt,
                                                       b1, nullptr, nullptr, h1, N);

    // ---- layer 2 + fused fc ----
    gemm_tile<HID><<<(N + 63) / 64, 256, 0, stream>>>(h1, W2, disqrt, t1, N);
    agg_kernel<true><<<(N + 3) / 4, 256, 0, stream>>>(t1, row_off, col, disqrt,
                                                      b2, Wfc, bfc, out, N);
}

// Round 6
// 329.893 us; speedup vs baseline: 1.7674x; 1.7674x over previous
//
#include <hip/hip_runtime.h>
#include <hip/hip_bf16.h>

// GCN: 2x GCNConv(+self-loops, sym-norm) + ReLU, then Linear(64->1).
// N=100000 nodes, E=1600000 edges, IN=128, HID=64, OUT=1.
//
//  - R5 fix: bin_edges still had 8B-random-scatter writes (63MB HBM for
//    12.8MB logical) + 8x edge-list re-read -> 310us. Replaced by an EXACT
//    two-level counting sort where every write is (nearly) sequential:
//      hist1: per-256-block LDS histogram of 98 coarse buckets (dst>>10)
//      scan_mat: exclusive scan of (bucket x block) matrix -> private
//                contiguous segments for every (block,bucket)
//      scatter1: append (src,dst) via LDS cursors -> ~512B seq runs
//      build_csr: 1 block/bucket: LDS hist of 1024 nodes (deg/disqrt/
//                row_off exact), wave scan, col scatter in 65KB window
//  - norm factored into GEMM epilogue: out[d]=dq_d*(Ts[d]+sum Ts[s]).
//  - 64x64 tiled GEMM, 4x4 register blocking, LDS-staged transposed X.
//  - agg: one wave per node, edge loop unrolled x8, scalar gather base.

#define IN_DIM 128
#define HID 64
#define B1 256        // level-1 blocks (chunks)
#define MAXNC 128     // max coarse buckets (N <= 131072)

// ---------------- level-1 histogram: 98 coarse buckets per chunk ----------------
__global__ __launch_bounds__(512) void hist1(const int* __restrict__ dst,
                                             int* __restrict__ ghist,
                                             int E, int NC, int chunk) {
    __shared__ int h[MAXNC];
    int t = threadIdx.x, blk = blockIdx.x;
    if (t < NC) h[t] = 0;
    __syncthreads();
    int s = blk * chunk, e = min(E, s + chunk);
    for (int i = s + t; i < e; i += 512) atomicAdd(&h[dst[i] >> 10], 1);
    __syncthreads();
    if (t < NC) ghist[(size_t)t * B1 + blk] = h[t];
}

// ---------------- exclusive scan of ghist (NC*B1 elems, in place) ----------------
__global__ __launch_bounds__(1024) void scan_mat(int* __restrict__ a, int M,
                                                 int* __restrict__ row_off, int N) {
    __shared__ int ws[16], wsoff[16], total_s;
    int t = threadIdx.x;
    int seg = (M + 1023) >> 10;
    int s = t * seg, e = min(M, s + seg);
    int sum = 0;
    for (int i = s; i < e; ++i) sum += a[i];
    int incl = sum;
#pragma unroll
    for (int o = 1; o < 64; o <<= 1) {
        int u = __shfl_up(incl, o, 64);
        if ((t & 63) >= o) incl += u;
    }
    if ((t & 63) == 63) ws[t >> 6] = incl;
    __syncthreads();
    if (t == 0) {
        int run = 0;
#pragma unroll
        for (int i = 0; i < 16; ++i) { wsoff[i] = run; run += ws[i]; }
        total_s = run;
    }
    __syncthreads();
    int run = wsoff[t >> 6] + incl - sum;  // exclusive prefix at segment start
    for (int i = s; i < e; ++i) { int tmp = a[i]; a[i] = run; run += tmp; }
    if (t == 0) row_off[N] = total_s;  // == E
}

// ---------------- level-1 scatter: sequential runs per (block,bucket) ----------------
__global__ __launch_bounds__(512) void scatter1(const int* __restrict__ src,
                                                const int* __restrict__ dst,
                                                const int* __restrict__ goff,
                                                int2* __restrict__ pairs,
                                                int E, int NC, int chunk) {
    __shared__ int cur[MAXNC];
    int t = threadIdx.x, blk = blockIdx.x;
    if (t < NC) cur[t] = goff[(size_t)t * B1 + blk];
    __syncthreads();
    int s = blk * chunk, e = min(E, s + chunk);
    for (int i = s + t; i < e; i += 512) {
        int d = dst[i];
        int p = atomicAdd(&cur[d >> 10], 1);  // LDS cursor holds global pos
        pairs[p] = make_int2(src[i], d);
    }
}

// ---------------- level-2: per-bucket CSR build (exact) ----------------
__global__ __launch_bounds__(1024) void build_csr(const int2* __restrict__ pairs,
                                                  const int* __restrict__ goff,
                                                  int* __restrict__ row_off,
                                                  float* __restrict__ disqrt,
                                                  int* __restrict__ col,
                                                  int E, int NC, int N) {
    __shared__ int h[1024], cur[1024];
    __shared__ int ws[16], wsoff[16];
    int b = blockIdx.x, t = threadIdx.x;
    int base = goff[(size_t)b * B1];
    int next = (b + 1 < NC) ? goff[(size_t)(b + 1) * B1] : E;
    h[t] = 0;
    __syncthreads();
    for (int i = base + t; i < next; i += 1024)
        atomicAdd(&h[pairs[i].y & 1023], 1);
    __syncthreads();
    int deg = h[t];
    int incl = deg;
#pragma unroll
    for (int o = 1; o < 64; o <<= 1) {
        int u = __shfl_up(incl, o, 64);
        if ((t & 63) >= o) incl += u;
    }
    if ((t & 63) == 63) ws[t >> 6] = incl;
    __syncthreads();
    if (t == 0) {
        int run = 0;
#pragma unroll
        for (int i = 0; i < 16; ++i) { wsoff[i] = run; run += ws[i]; }
    }
    __syncthreads();
    int excl = wsoff[t >> 6] + incl - deg;
    cur[t] = base + excl;
    int node = (b << 10) + t;
    if (node < N) {
        row_off[node] = base + excl;
        disqrt[node]  = rsqrtf((float)(deg + 1));  // +1 self-loop
    }
    __syncthreads();
    for (int i = base + t; i < next; i += 1024) {
        int2 p = pairs[i];
        int pos = atomicAdd(&cur[p.y & 1023], 1);  // LDS atomic, global pos
        col[pos] = p.x;                            // 65KB window, single XCD
    }
}

// ---------------- tiled GEMM: Ts[n,64] = (X[n,K] @ W[K,64]) * disqrt[n] ----------------
template <int K>
__global__ __launch_bounds__(256) void gemm_tile(const float* __restrict__ X,
                                                 const float* __restrict__ W,
                                                 const float* __restrict__ disqrt,
                                                 float* __restrict__ Ts, int n) {
    __shared__ float xs[32][68];   // [k][m]; stride 68 floats keeps rows 16B-aligned
    __shared__ float ws[32][64];   // [k][c]
    const int tid  = threadIdx.x;
    const int nIdx = tid & 15;     // cols 4*nIdx..+3
    const int mIdx = tid >> 4;     // nodes 4*mIdx..+3
    const int m0   = blockIdx.x * 64;
    float acc[4][4] = {};
    for (int kc = 0; kc < K; kc += 32) {
        int f = tid;
#pragma unroll
        for (int i = 0; i < 2; ++i, f += 256) {
            int r  = f >> 3;           // 0..63
            int kq = f & 7;            // float4 within chunk
            int row = m0 + r;
            float4 g = make_float4(0.f, 0.f, 0.f, 0.f);
            if (row < n) g = *(const float4*)(X + (size_t)row * K + kc + 4 * kq);
            xs[4 * kq + 0][r] = g.x;
            xs[4 * kq + 1][r] = g.y;
            xs[4 * kq + 2][r] = g.z;
            xs[4 * kq + 3][r] = g.w;
        }
        f = tid;
#pragma unroll
        for (int i = 0; i < 2; ++i, f += 256) {
            int kk = f >> 4;           // 0..31
            int cq = f & 15;           // 0..15
            *(float4*)&ws[kk][4 * cq] =
                *(const float4*)(W + (size_t)(kc + kk) * 64 + 4 * cq);
        }
        __syncthreads();
#pragma unroll 4
        for (int k = 0; k < 32; ++k) {
            float4 a = *(const float4*)&xs[k][4 * mIdx];
            float4 b = *(const float4*)&ws[k][4 * nIdx];
            const float* ap = (const float*)&a;
            const float* bp = (const float*)&b;
#pragma unroll
            for (int mi = 0; mi < 4; ++mi)
#pragma unroll
                for (int ni = 0; ni < 4; ++ni)
                    acc[mi][ni] += ap[mi] * bp[ni];
        }
        __syncthreads();
    }
#pragma unroll
    for (int mi = 0; mi < 4; ++mi) {
        int row = m0 + 4 * mIdx + mi;
        if (row < n) {
            float s = disqrt[row];
            *(float4*)(Ts + (size_t)row * 64 + 4 * nIdx) =
                make_float4(acc[mi][0] * s, acc[mi][1] * s,
                            acc[mi][2] * s, acc[mi][3] * s);
        }
    }
}

// ---------------- aggregation: one wave per node, 8 gathers in flight ----------------
// out[d] = relu(disqrt[d] * (Ts[d] + sum_e Ts[col[e]]) + bias)
template <bool FUSE_FC>
__global__ __launch_bounds__(256) void agg_kernel(const float* __restrict__ Ts,
                                                  const int* __restrict__ row_off,
                                                  const int* __restrict__ col,
                                                  const float* __restrict__ disqrt,
                                                  const float* __restrict__ bias,
                                                  const float* __restrict__ wfc,
                                                  const float* __restrict__ bfc,
                                                  float* __restrict__ out, int n) {
    int node = blockIdx.x * 4 + (threadIdx.x >> 6);
    if (node >= n) return;
    int lane = threadIdx.x & 63;
    float acc = Ts[(size_t)node * HID + lane];  // self-loop (pre-scaled)
    int beg = __builtin_amdgcn_readfirstlane(row_off[node]);
    int end = __builtin_amdgcn_readfirstlane(row_off[node + 1]);
    int i = beg;
    for (; i + 8 <= end; i += 8) {
        int s0 = __builtin_amdgcn_readfirstlane(col[i + 0]);
        int s1 = __builtin_amdgcn_readfirstlane(col[i + 1]);
        int s2 = __builtin_amdgcn_readfirstlane(col[i + 2]);
        int s3 = __builtin_amdgcn_readfirstlane(col[i + 3]);
        int s4 = __builtin_amdgcn_readfirstlane(col[i + 4]);
        int s5 = __builtin_amdgcn_readfirstlane(col[i + 5]);
        int s6 = __builtin_amdgcn_readfirstlane(col[i + 6]);
        int s7 = __builtin_amdgcn_readfirstlane(col[i + 7]);
        float g0 = Ts[(size_t)s0 * HID + lane];
        float g1 = Ts[(size_t)s1 * HID + lane];
        float g2 = Ts[(size_t)s2 * HID + lane];
        float g3 = Ts[(size_t)s3 * HID + lane];
        float g4 = Ts[(size_t)s4 * HID + lane];
        float g5 = Ts[(size_t)s5 * HID + lane];
        float g6 = Ts[(size_t)s6 * HID + lane];
        float g7 = Ts[(size_t)s7 * HID + lane];
        acc += g0; acc += g1; acc += g2; acc += g3;
        acc += g4; acc += g5; acc += g6; acc += g7;
    }
    for (; i < end; ++i) {
        int s = __builtin_amdgcn_readfirstlane(col[i]);
        acc += Ts[(size_t)s * HID + lane];
    }
    float r = fmaxf(acc * disqrt[node] + bias[lane], 0.f);
    if (!FUSE_FC) {
        out[(size_t)node * HID + lane] = r;
    } else {
        float v = r * wfc[lane];
        v += __shfl_down(v, 32, 64);
        v += __shfl_down(v, 16, 64);
        v += __shfl_down(v, 8, 64);
        v += __shfl_down(v, 4, 64);
        v += __shfl_down(v, 2, 64);
        v += __shfl_down(v, 1, 64);
        if (lane == 0) out[node] = v + bfc[0];
    }
}

extern "C" void kernel_launch(void* const* d_in, const int* in_sizes, int n_in,
                              void* d_out, int out_size, void* d_ws, size_t ws_size,
                              hipStream_t stream) {
    const float* x   = (const float*)d_in[0];
    const int*   ei  = (const int*)d_in[1];
    const float* W1  = (const float*)d_in[2];
    const float* b1  = (const float*)d_in[3];
    const float* W2  = (const float*)d_in[4];
    const float* b2  = (const float*)d_in[5];
    const float* Wfc = (const float*)d_in[6];
    const float* bfc = (const float*)d_in[7];
    float* out = (float*)d_out;

    const int N = in_sizes[0] / IN_DIM;
    const int E = in_sizes[1] / 2;
    const int* src = ei;
    const int* dst = ei + E;
    const int NC    = (N + 1023) >> 10;      // coarse buckets (1024 nodes each)
    const int chunk = (E + B1 - 1) / B1;     // edges per level-1 block

    // ---- workspace carve-up (256B aligned) ----
    char* w = (char*)d_ws;
    auto alloc = [&](size_t bytes) {
        void* p = (void*)w;
        w += (bytes + 255) & ~(size_t)255;
        return p;
    };
    int*   row_off = (int*)alloc((size_t)(N + 1) * 4);
    float* disqrt  = (float*)alloc((size_t)N * 4);
    int*   goff    = (int*)alloc((size_t)NC * B1 * 4);
    int*   col     = (int*)alloc((size_t)E * 4);
    float* t1      = (float*)alloc((size_t)N * HID * 4);  // reused: pairs, then Ts
    float* h1      = (float*)alloc((size_t)N * HID * 4);
    int2*  pairs   = (int2*)t1;  // E*8 = 12.8MB <= N*HID*4 = 25.6MB

    // ---- build CSR (exact two-level counting sort) ----
    hist1<<<B1, 512, 0, stream>>>(dst, goff, E, NC, chunk);
    scan_mat<<<1, 1024, 0, stream>>>(goff, NC * B1, row_off, N);
    scatter1<<<B1, 512, 0, stream>>>(src, dst, goff, pairs, E, NC, chunk);
    build_csr<<<NC, 1024, 0, stream>>>(pairs, goff, row_off, disqrt, col, E, NC, N);

    // ---- layer 1 ----
    gemm_tile<IN_DIM><<<(N + 63) / 64, 256, 0, stream>>>(x, W1, disqrt, t1, N);
    agg_kernel<false><<<(N + 3) / 4, 256, 0, stream>>>(t1, row_off, col, disqrt,
                                                       b1, nullptr, nullptr, h1, N);

    // ---- layer 2 + fused fc ----
    gemm_tile<HID><<<(N + 63) / 64, 256, 0, stream>>>(h1, W2, disqrt, t1, N);
    agg_kernel<true><<<(N + 3) / 4, 256, 0, stream>>>(t1, row_off, col, disqrt,
                                                      b2, Wfc, bfc, out, N);
}

// Round 7
// 320.096 us; speedup vs baseline: 1.8215x; 1.0306x over previous
//
#include <hip/hip_runtime.h>
#include <hip/hip_bf16.h>

// GCN: 2x GCNConv(+self-loops, sym-norm) + ReLU, then Linear(64->1).
// N=100000 nodes, E=1600000 edges, IN=128, HID=64, OUT=1.
//
//  - R6 fix: agg gather was 193MB FETCH per dispatch (256B/edge random
//    gather over 25.6MB Ts, ~7.5x refetch; >L2/XCD). Ts now stored bf16
//    (packed bf16x2): gather = 128B/edge, fp32 accumulate. Agg uses a
//    half-wave per edge (lane = bf16x2 pair), 2 edges/step, 8 in flight.
//  - Exact two-level counting sort CSR build (R5): hist1 -> scan_mat ->
//    scatter1 (sequential segment writes) -> build_csr (per-1024-node
//    bucket LDS histogram/scan/scatter; deg/disqrt/row_off exact).
//  - norm factored into GEMM epilogue: out[d]=dq_d*(Ts[d]+sum Ts[s]).
//  - 64x64 tiled GEMM, 4x4 register blocking, LDS-staged transposed X.

#define IN_DIM 128
#define HID 64
#define B1 256        // level-1 blocks (chunks)
#define MAXNC 128     // max coarse buckets (N <= 131072)

typedef unsigned int uint;

__device__ inline uint pack_bf16x2(float a, float b) {
    uint ua = __builtin_bit_cast(uint, a);
    uint ub = __builtin_bit_cast(uint, b);
    ua += 0x7fffu + ((ua >> 16) & 1u);   // RNE
    ub += 0x7fffu + ((ub >> 16) & 1u);
    return (ua >> 16) | (ub & 0xffff0000u);
}
__device__ inline float bf_lo(uint g) { return __builtin_bit_cast(float, g << 16); }
__device__ inline float bf_hi(uint g) { return __builtin_bit_cast(float, g & 0xffff0000u); }

// ---------------- level-1 histogram: coarse buckets (dst>>10) per chunk ----------------
__global__ __launch_bounds__(512) void hist1(const int* __restrict__ dst,
                                             int* __restrict__ ghist,
                                             int E, int NC, int chunk) {
    __shared__ int h[MAXNC];
    int t = threadIdx.x, blk = blockIdx.x;
    if (t < NC) h[t] = 0;
    __syncthreads();
    int s = blk * chunk, e = min(E, s + chunk);
    for (int i = s + t; i < e; i += 512) atomicAdd(&h[dst[i] >> 10], 1);
    __syncthreads();
    if (t < NC) ghist[(size_t)t * B1 + blk] = h[t];
}

// ---------------- exclusive scan of ghist (NC*B1 elems, in place) ----------------
__global__ __launch_bounds__(1024) void scan_mat(int* __restrict__ a, int M,
                                                 int* __restrict__ row_off, int N) {
    __shared__ int ws[16], wsoff[16], total_s;
    int t = threadIdx.x;
    int seg = (M + 1023) >> 10;
    int s = t * seg, e = min(M, s + seg);
    int sum = 0;
    for (int i = s; i < e; ++i) sum += a[i];
    int incl = sum;
#pragma unroll
    for (int o = 1; o < 64; o <<= 1) {
        int u = __shfl_up(incl, o, 64);
        if ((t & 63) >= o) incl += u;
    }
    if ((t & 63) == 63) ws[t >> 6] = incl;
    __syncthreads();
    if (t == 0) {
        int run = 0;
#pragma unroll
        for (int i = 0; i < 16; ++i) { wsoff[i] = run; run += ws[i]; }
        total_s = run;
    }
    __syncthreads();
    int run = wsoff[t >> 6] + incl - sum;  // exclusive prefix at segment start
    for (int i = s; i < e; ++i) { int tmp = a[i]; a[i] = run; run += tmp; }
    if (t == 0) row_off[N] = total_s;  // == E
}

// ---------------- level-1 scatter: sequential runs per (block,bucket) ----------------
__global__ __launch_bounds__(512) void scatter1(const int* __restrict__ src,
                                                const int* __restrict__ dst,
                                                const int* __restrict__ goff,
                                                int2* __restrict__ pairs,
                                                int E, int NC, int chunk) {
    __shared__ int cur[MAXNC];
    int t = threadIdx.x, blk = blockIdx.x;
    if (t < NC) cur[t] = goff[(size_t)t * B1 + blk];
    __syncthreads();
    int s = blk * chunk, e = min(E, s + chunk);
    for (int i = s + t; i < e; i += 512) {
        int d = dst[i];
        int p = atomicAdd(&cur[d >> 10], 1);  // LDS cursor holds global pos
        pairs[p] = make_int2(src[i], d);
    }
}

// ---------------- level-2: per-bucket CSR build (exact) ----------------
__global__ __launch_bounds__(1024) void build_csr(const int2* __restrict__ pairs,
                                                  const int* __restrict__ goff,
                                                  int* __restrict__ row_off,
                                                  float* __restrict__ disqrt,
                                                  int* __restrict__ col,
                                                  int E, int NC, int N) {
    __shared__ int h[1024], cur[1024];
    __shared__ int ws[16], wsoff[16];
    int b = blockIdx.x, t = threadIdx.x;
    int base = goff[(size_t)b * B1];
    int next = (b + 1 < NC) ? goff[(size_t)(b + 1) * B1] : E;
    h[t] = 0;
    __syncthreads();
    for (int i = base + t; i < next; i += 1024)
        atomicAdd(&h[pairs[i].y & 1023], 1);
    __syncthreads();
    int deg = h[t];
    int incl = deg;
#pragma unroll
    for (int o = 1; o < 64; o <<= 1) {
        int u = __shfl_up(incl, o, 64);
        if ((t & 63) >= o) incl += u;
    }
    if ((t & 63) == 63) ws[t >> 6] = incl;
    __syncthreads();
    if (t == 0) {
        int run = 0;
#pragma unroll
        for (int i = 0; i < 16; ++i) { wsoff[i] = run; run += ws[i]; }
    }
    __syncthreads();
    int excl = wsoff[t >> 6] + incl - deg;
    cur[t] = base + excl;
    int node = (b << 10) + t;
    if (node < N) {
        row_off[node] = base + excl;
        disqrt[node]  = rsqrtf((float)(deg + 1));  // +1 self-loop
    }
    __syncthreads();
    for (int i = base + t; i < next; i += 1024) {
        int2 p = pairs[i];
        int pos = atomicAdd(&cur[p.y & 1023], 1);  // LDS atomic, global pos
        col[pos] = p.x;                            // 65KB window, single XCD
    }
}

// ---------------- tiled GEMM: Ts_bf16[n,64] = (X[n,K] @ W[K,64]) * disqrt[n] ----------------
template <int K>
__global__ __launch_bounds__(256) void gemm_tile(const float* __restrict__ X,
                                                 const float* __restrict__ W,
                                                 const float* __restrict__ disqrt,
                                                 uint* __restrict__ Tsb, int n) {
    __shared__ float xs[32][68];   // [k][m]; stride 68 floats keeps rows 16B-aligned
    __shared__ float ws[32][64];   // [k][c]
    const int tid  = threadIdx.x;
    const int nIdx = tid & 15;     // cols 4*nIdx..+3
    const int mIdx = tid >> 4;     // nodes 4*mIdx..+3
    const int m0   = blockIdx.x * 64;
    float acc[4][4] = {};
    for (int kc = 0; kc < K; kc += 32) {
        int f = tid;
#pragma unroll
        for (int i = 0; i < 2; ++i, f += 256) {
            int r  = f >> 3;           // 0..63
            int kq = f & 7;            // float4 within chunk
            int row = m0 + r;
            float4 g = make_float4(0.f, 0.f, 0.f, 0.f);
            if (row < n) g = *(const float4*)(X + (size_t)row * K + kc + 4 * kq);
            xs[4 * kq + 0][r] = g.x;
            xs[4 * kq + 1][r] = g.y;
            xs[4 * kq + 2][r] = g.z;
            xs[4 * kq + 3][r] = g.w;
        }
        f = tid;
#pragma unroll
        for (int i = 0; i < 2; ++i, f += 256) {
            int kk = f >> 4;           // 0..31
            int cq = f & 15;           // 0..15
            *(float4*)&ws[kk][4 * cq] =
                *(const float4*)(W + (size_t)(kc + kk) * 64 + 4 * cq);
        }
        __syncthreads();
#pragma unroll 4
        for (int k = 0; k < 32; ++k) {
            float4 a = *(const float4*)&xs[k][4 * mIdx];
            float4 b = *(const float4*)&ws[k][4 * nIdx];
            const float* ap = (const float*)&a;
            const float* bp = (const float*)&b;
#pragma unroll
            for (int mi = 0; mi < 4; ++mi)
#pragma unroll
                for (int ni = 0; ni < 4; ++ni)
                    acc[mi][ni] += ap[mi] * bp[ni];
        }
        __syncthreads();
    }
#pragma unroll
    for (int mi = 0; mi < 4; ++mi) {
        int row = m0 + 4 * mIdx + mi;
        if (row < n) {
            float s = disqrt[row];
            uint2 pk;
            pk.x = pack_bf16x2(acc[mi][0] * s, acc[mi][1] * s);
            pk.y = pack_bf16x2(acc[mi][2] * s, acc[mi][3] * s);
            *(uint2*)(Tsb + (size_t)row * 32 + 2 * nIdx) = pk;
        }
    }
}

// ---------------- aggregation: wave per node, half-wave per edge ----------------
// out[d] = relu(disqrt[d] * (Ts[d] + sum_e Ts[col[e]]) + bias)
// Tsb: packed bf16x2, 32 uints per node row (128B). Lane = feature pair.
template <bool FUSE_FC>
__global__ __launch_bounds__(256) void agg_kernel(const uint* __restrict__ Tsb,
                                                  const int* __restrict__ row_off,
                                                  const int* __restrict__ col,
                                                  const float* __restrict__ disqrt,
                                                  const float* __restrict__ bias,
                                                  const float* __restrict__ wfc,
                                                  const float* __restrict__ bfc,
                                                  float* __restrict__ out, int n) {
    int node = blockIdx.x * 4 + (threadIdx.x >> 6);
    if (node >= n) return;
    int lane = threadIdx.x & 63;
    int h = lane >> 5;      // half-wave id: which edge of a pair
    int p = lane & 31;      // feature pair index (features 2p, 2p+1)
    float2 acc = make_float2(0.f, 0.f);
    {   // self-loop (half 0 only)
        uint g = Tsb[(size_t)node * 32 + p];
        if (h == 0) { acc.x += bf_lo(g); acc.y += bf_hi(g); }
    }
    int beg = __builtin_amdgcn_readfirstlane(row_off[node]);
    int end = __builtin_amdgcn_readfirstlane(row_off[node + 1]);
    int i = beg;
    for (; i + 8 <= end; i += 8) {       // 8 edges: 4 per half, all in flight
        int e = i + h;
        int s0 = col[e + 0];
        int s1 = col[e + 2];
        int s2 = col[e + 4];
        int s3 = col[e + 6];
        uint g0 = Tsb[(size_t)s0 * 32 + p];
        uint g1 = Tsb[(size_t)s1 * 32 + p];
        uint g2 = Tsb[(size_t)s2 * 32 + p];
        uint g3 = Tsb[(size_t)s3 * 32 + p];
        acc.x += bf_lo(g0); acc.y += bf_hi(g0);
        acc.x += bf_lo(g1); acc.y += bf_hi(g1);
        acc.x += bf_lo(g2); acc.y += bf_hi(g2);
        acc.x += bf_lo(g3); acc.y += bf_hi(g3);
    }
    for (; i + 2 <= end; i += 2) {       // pair
        int s = col[i + h];
        uint g = Tsb[(size_t)s * 32 + p];
        acc.x += bf_lo(g); acc.y += bf_hi(g);
    }
    if (i < end) {                       // odd leftover: half 0 only
        int s = col[i];
        uint g = Tsb[(size_t)s * 32 + p];
        if (h == 0) { acc.x += bf_lo(g); acc.y += bf_hi(g); }
    }
    // combine halves
    acc.x += __shfl_xor(acc.x, 32, 64);
    acc.y += __shfl_xor(acc.y, 32, 64);
    float dq = disqrt[node];
    float2 bv = *(const float2*)(bias + 2 * p);
    float rx = fmaxf(acc.x * dq + bv.x, 0.f);
    float ry = fmaxf(acc.y * dq + bv.y, 0.f);
    if (!FUSE_FC) {
        if (h == 0)
            *(float2*)(out + (size_t)node * HID + 2 * p) = make_float2(rx, ry);
    } else {
        float2 wv = *(const float2*)(wfc + 2 * p);
        float v = rx * wv.x + ry * wv.y;
        v += __shfl_down(v, 16, 64);
        v += __shfl_down(v, 8, 64);
        v += __shfl_down(v, 4, 64);
        v += __shfl_down(v, 2, 64);
        v += __shfl_down(v, 1, 64);
        if (lane == 0) out[node] = v + bfc[0];
    }
}

extern "C" void kernel_launch(void* const* d_in, const int* in_sizes, int n_in,
                              void* d_out, int out_size, void* d_ws, size_t ws_size,
                              hipStream_t stream) {
    const float* x   = (const float*)d_in[0];
    const int*   ei  = (const int*)d_in[1];
    const float* W1  = (const float*)d_in[2];
    const float* b1  = (const float*)d_in[3];
    const float* W2  = (const float*)d_in[4];
    const float* b2  = (const float*)d_in[5];
    const float* Wfc = (const float*)d_in[6];
    const float* bfc = (const float*)d_in[7];
    float* out = (float*)d_out;

    const int N = in_sizes[0] / IN_DIM;
    const int E = in_sizes[1] / 2;
    const int* src = ei;
    const int* dst = ei + E;
    const int NC    = (N + 1023) >> 10;      // coarse buckets (1024 nodes each)
    const int chunk = (E + B1 - 1) / B1;     // edges per level-1 block

    // ---- workspace carve-up (256B aligned) ----
    char* w = (char*)d_ws;
    auto alloc = [&](size_t bytes) {
        void* p = (void*)w;
        w += (bytes + 255) & ~(size_t)255;
        return p;
    };
    int*   row_off = (int*)alloc((size_t)(N + 1) * 4);
    float* disqrt  = (float*)alloc((size_t)N * 4);
    int*   goff    = (int*)alloc((size_t)NC * B1 * 4);
    int*   col     = (int*)alloc((size_t)E * 4);
    // scratch region reused: pairs (E*8) first, then Ts bf16 (N*128B)
    size_t scrA = (size_t)E * 8, scrB = (size_t)N * HID * 2;
    void*  scr  = alloc(scrA > scrB ? scrA : scrB);
    float* h1   = (float*)alloc((size_t)N * HID * 4);
    int2*  pairs = (int2*)scr;
    uint*  Tsb   = (uint*)scr;

    // ---- build CSR (exact two-level counting sort) ----
    hist1<<<B1, 512, 0, stream>>>(dst, goff, E, NC, chunk);
    scan_mat<<<1, 1024, 0, stream>>>(goff, NC * B1, row_off, N);
    scatter1<<<B1, 512, 0, stream>>>(src, dst, goff, pairs, E, NC, chunk);
    build_csr<<<NC, 1024, 0, stream>>>(pairs, goff, row_off, disqrt, col, E, NC, N);

    // ---- layer 1 ----
    gemm_tile<IN_DIM><<<(N + 63) / 64, 256, 0, stream>>>(x, W1, disqrt, Tsb, N);
    agg_kernel<false><<<(N + 3) / 4, 256, 0, stream>>>(Tsb, row_off, col, disqrt,
                                                       b1, nullptr, nullptr, h1, N);

    // ---- layer 2 + fused fc ----
    gemm_tile<HID><<<(N + 63) / 64, 256, 0, stream>>>(h1, W2, disqrt, Tsb, N);
    agg_kernel<true><<<(N + 3) / 4, 256, 0, stream>>>(Tsb, row_off, col, disqrt,
                                                      b2, Wfc, bfc, out, N);
}